// Round 10
// baseline (101.143 us; speedup 1.0000x reference)
//
#include <hip/hip_runtime.h>
#include <math.h>

#define BB 8
#define CC 512
#define HWSZ 6400
#define NN 100
#define HR 40
#define WR 40
#define VV 20        // N_CLASSES_FG
#define VO 21        // BG + FG
#define TPX 1280     // pixels per px-major tile
#define NTT 5        // tiles per image (6400/1280)
#define NG 8         // channel groups
#define GC 64        // channels per group
#define THR 320      // threads per px-major block (5 waves)

typedef unsigned long long u64;
typedef float f4 __attribute__((ext_vector_type(4)));

// order-preserving float -> uint32 map (min float == min uint)
__device__ __forceinline__ unsigned mapf(float f) {
    unsigned b = __float_as_uint(f);
    return (b & 0x80000000u) ? ~b : (b | 0x80000000u);
}
// f32 -> bf16 round-nearest-even
__device__ __forceinline__ unsigned short f2bf(float f) {
    unsigned u = __float_as_uint(f);
    return (unsigned short)((u + 0x7fffu + ((u >> 16) & 1u)) >> 16);
}
__device__ __forceinline__ float bf2f(unsigned short h) {
    return __uint_as_float(((unsigned)h) << 16);
}

// ---------------- K1: normalized prototypes, transposed [c][v]; init batchMin
__global__ __launch_bounds__(512) void k_protos(const float* __restrict__ refc,
                                                const int* __restrict__ coord,
                                                const int* __restrict__ cls,
                                                float* __restrict__ protosT,
                                                u64* __restrict__ batchMin) {
    const int v = blockIdx.x;        // class
    const int c = threadIdx.x;       // channel
    if (v == 0 && c < BB) batchMin[c] = ~0ull;

    float acc = 0.f;
    int cnt = 0;
    for (int n = 0; n < NN; ++n) {
        if (cls[n] == v) {           // uniform across block
            int y = coord[2 * n + 1];
            int x = coord[2 * n + 0];
            acc += refc[((size_t)(n * CC + c) * HR + y) * WR + x];
            ++cnt;
        }
    }
    acc /= fmaxf((float)cnt, 1.0f);

    float ss = acc * acc;
    #pragma unroll
    for (int off = 32; off; off >>= 1) ss += __shfl_xor(ss, off);
    __shared__ float sW[8];
    const int wave = c >> 6, lane = c & 63;
    if (lane == 0) sW[wave] = ss;
    __syncthreads();
    float tot = 0.f;
    #pragma unroll
    for (int w = 0; w < 8; ++w) tot += sW[w];
    float scale = 1.0f / fmaxf(sqrtf(tot), 1e-10f);

    protosT[c * VV + v] = acc * scale;
}

// ---------------- K2: px-major partial prob_C -------------------------------
// grid = 8b x 5tiles x 8groups = 320; block = 320 threads (5 waves).
// All waves walk the SAME channel row together: 320x16B = 5KB contiguous burst
// per channel step. No LDS, no syncthreads. Channel is block-uniform -> protos
// ride the scalar pipe. Partials: d rows in bf16, ss + sum_v(d) rows in f32.
__global__ __launch_bounds__(THR) void k_probC_part(const float* __restrict__ codeC,
                                                    const float* __restrict__ protosT,
                                                    unsigned short* __restrict__ dBf,
                                                    float* __restrict__ ssf,
                                                    float* __restrict__ Sf) {
    const int t    = threadIdx.x;
    const int blk  = blockIdx.x;
    const int g    = blk & 7;
    const int tile = (blk >> 3) % NTT;
    const int b    = blk / (NG * NTT);

    const float* src = codeC + ((size_t)(b * CC + g * GC)) * HWSZ + tile * TPX + 4 * t;
    const float* pt  = protosT + (size_t)(g * GC) * VV;   // block-uniform -> s_load

    f4 d[VV];
    #pragma unroll
    for (int v = 0; v < VV; ++v) d[v] = (f4)(0.f);
    f4 ss = (f4)(0.f);

    #pragma unroll 8
    for (int c = 0; c < GC; ++c) {
        f4 x = *(const f4*)(src + (size_t)c * HWSZ);
        ss.x = fmaf(x.x, x.x, ss.x);
        ss.y = fmaf(x.y, x.y, ss.y);
        ss.z = fmaf(x.z, x.z, ss.z);
        ss.w = fmaf(x.w, x.w, ss.w);
        const float* pr = pt + c * VV;
        #pragma unroll
        for (int v = 0; v < VV; ++v) {
            float p = pr[v];
            d[v].x = fmaf(x.x, p, d[v].x);
            d[v].y = fmaf(x.y, p, d[v].y);
            d[v].z = fmaf(x.z, p, d[v].z);
            d[v].w = fmaf(x.w, p, d[v].w);
        }
    }

    // stores: coalesced, thread -> 8B (bf16x4) or 16B (f4) at px 4*t
    unsigned short* dB = dBf + (size_t)blk * (VV * TPX) + 4 * t;
    f4 S = (f4)(0.f);
    #pragma unroll
    for (int v = 0; v < VV; ++v) {
        ushort4 h;
        h.x = f2bf(d[v].x); h.y = f2bf(d[v].y); h.z = f2bf(d[v].z); h.w = f2bf(d[v].w);
        *(ushort4*)(dB + (size_t)v * TPX) = h;
        S.x += d[v].x; S.y += d[v].y; S.z += d[v].z; S.w += d[v].w;
    }
    *(f4*)(ssf + (size_t)blk * TPX + 4 * t) = ss;
    *(f4*)(Sf  + (size_t)blk * TPX + 4 * t) = S;
}

// ---------------- K2b: combine 8 groups -> probC + psum + argmin ------------
// grid = 8b x 25 px-chunks(256) = 200; block = 256 (thread = pixel).
__global__ __launch_bounds__(256) void k_finishC(const unsigned short* __restrict__ dBf,
                                                 const float* __restrict__ ssf,
                                                 const float* __restrict__ Sf,
                                                 float* __restrict__ probC,
                                                 u64* __restrict__ batchMin) {
    __shared__ u64 sKey[4];
    const int tid   = threadIdx.x;
    const int chunk = blockIdx.x % 25;
    const int b     = blockIdx.x / 25;
    const int tile  = chunk / 5;                 // 1280 = 5 x 256
    const int pxp   = (chunk % 5) * 256 + tid;   // px within tile
    const int px    = tile * TPX + pxp;          // global px
    const int base  = (b * NTT + tile) * NG;

    float ssT = 0.f, ST = 0.f;
    #pragma unroll
    for (int g = 0; g < NG; ++g) {
        ssT += ssf[(size_t)(base + g) * TPX + pxp];
        ST  += Sf [(size_t)(base + g) * TPX + pxp];
    }
    float scale = 1.0f / fmaxf(sqrtf(ssT), 1e-10f);

    float* dst = probC + (size_t)b * VV * HWSZ + px;
    #pragma unroll
    for (int v = 0; v < VV; ++v) {
        float dv = 0.f;
        #pragma unroll
        for (int g = 0; g < NG; ++g)
            dv += bf2f(dBf[(size_t)(base + g) * (VV * TPX) + v * TPX + pxp]);
        dst[(size_t)v * HWSZ] = dv * scale;
    }

    float psum = ST * scale;   // f32-accurate argmin key
    u64 key = ((u64)mapf(psum) << 32) | (unsigned)px;
    #pragma unroll
    for (int off = 32; off; off >>= 1) {
        u64 o = __shfl_xor(key, off);
        if (o < key) key = o;
    }
    if ((tid & 63) == 0) sKey[tid >> 6] = key;
    __syncthreads();
    if (tid == 0) {
        u64 kk = sKey[0];
        kk = sKey[1] < kk ? sKey[1] : kk;
        kk = sKey[2] < kk ? sKey[2] : kk;
        kk = sKey[3] < kk ? sKey[3] : kk;
        atomicMin(&batchMin[b], kk);
    }
}

// ---------------- K3: normalize code_BG at the argmin pixel -----------------
__global__ __launch_bounds__(512) void k_minvec(const u64* __restrict__ batchMin,
                                                const float* __restrict__ codeBG,
                                                float* __restrict__ minvecN) {
    const int b = blockIdx.x, c = threadIdx.x;
    const int pix = (int)(unsigned)(batchMin[b] & 0xFFFFFFFFull);
    float x = codeBG[(size_t)(b * CC + c) * HWSZ + pix];
    float ss = x * x;
    #pragma unroll
    for (int off = 32; off; off >>= 1) ss += __shfl_xor(ss, off);
    __shared__ float sW[8];
    if ((c & 63) == 0) sW[c >> 6] = ss;
    __syncthreads();
    float tot = 0.f;
    #pragma unroll
    for (int w = 0; w < 8; ++w) tot += sW[w];
    minvecN[b * CC + c] = x * (1.0f / fmaxf(sqrtf(tot), 1e-10f));
}

// ---------------- K4: px-major partial prob_BG ------------------------------
// Same px-major structure as K2. Partials f32 (only 2 rows).
__global__ __launch_bounds__(THR) void k_bg_part(const float* __restrict__ codeBG,
                                                 const float* __restrict__ minvecN,
                                                 float* __restrict__ bgf) {
    const int t    = threadIdx.x;
    const int blk  = blockIdx.x;
    const int g    = blk & 7;
    const int tile = (blk >> 3) % NTT;
    const int b    = blk / (NG * NTT);

    const float* src = codeBG + ((size_t)(b * CC + g * GC)) * HWSZ + tile * TPX + 4 * t;
    const float* mv  = minvecN + b * CC + g * GC;   // block-uniform -> s_load

    f4 ss = (f4)(0.f);
    f4 dg = (f4)(0.f);

    #pragma unroll 8
    for (int c = 0; c < GC; ++c) {
        f4 x = *(const f4*)(src + (size_t)c * HWSZ);
        float m = mv[c];
        ss.x = fmaf(x.x, x.x, ss.x);
        ss.y = fmaf(x.y, x.y, ss.y);
        ss.z = fmaf(x.z, x.z, ss.z);
        ss.w = fmaf(x.w, x.w, ss.w);
        dg.x = fmaf(x.x, m, dg.x);
        dg.y = fmaf(x.y, m, dg.y);
        dg.z = fmaf(x.z, m, dg.z);
        dg.w = fmaf(x.w, m, dg.w);
    }

    *(f4*)(bgf + (size_t)blk * (2 * TPX) + 4 * t)       = ss;
    *(f4*)(bgf + (size_t)blk * (2 * TPX) + TPX + 4 * t) = dg;
}

// ---------------- K4b: combine 8 groups -> prob_BG + softmax + out ----------
__global__ __launch_bounds__(256) void k_finishBG(const float* __restrict__ bgf,
                                                  const float* __restrict__ probC,
                                                  float* __restrict__ out) {
    const int tid   = threadIdx.x;
    const int chunk = blockIdx.x % 25;
    const int b     = blockIdx.x / 25;
    const int tile  = chunk / 5;
    const int pxp   = (chunk % 5) * 256 + tid;
    const int px    = tile * TPX + pxp;
    const int base  = (b * NTT + tile) * NG;

    float ssT = 0.f, dgT = 0.f;
    #pragma unroll
    for (int g = 0; g < NG; ++g) {
        ssT += bgf[(size_t)(base + g) * (2 * TPX) + pxp];
        dgT += bgf[(size_t)(base + g) * (2 * TPX) + TPX + pxp];
    }
    float pbg = dgT * (1.0f / fmaxf(sqrtf(ssT), 1e-10f));

    float pv[VO];
    pv[0] = pbg;
    const float* pc = probC + (size_t)b * VV * HWSZ + px;
    #pragma unroll
    for (int v = 0; v < VV; ++v) pv[v + 1] = pc[(size_t)v * HWSZ];

    float m = pv[0];
    #pragma unroll
    for (int i = 1; i < VO; ++i) m = fmaxf(m, pv[i]);
    float se = 0.f;
    #pragma unroll
    for (int i = 0; i < VO; ++i) { pv[i] = __expf(pv[i] - m); se += pv[i]; }
    float inv = 1.0f / se;

    float* dstp = out + (size_t)b * VO * HWSZ + px;
    #pragma unroll
    for (int i = 0; i < VO; ++i) dstp[(size_t)i * HWSZ] = pv[i] * inv;
}

extern "C" void kernel_launch(void* const* d_in, const int* in_sizes, int n_in,
                              void* d_out, int out_size, void* d_ws, size_t ws_size,
                              hipStream_t stream) {
    const float* codeC  = (const float*)d_in[0];
    const float* codeBG = (const float*)d_in[1];
    const float* refc   = (const float*)d_in[2];
    // d_in[3] (ref_code_bg) unused by the reference
    const int* coord = (const int*)d_in[4];
    const int* cls   = (const int*)d_in[5];
    float* out = (float*)d_out;

    char* ws = (char*)d_ws;
    float*          protosT  = (float*)         (ws);             // 40,960 B
    float*          probC    = (float*)         (ws + 40960);     // 4,096,000 B
    float*          minvecN  = (float*)         (ws + 4136960);   // 16,384 B
    u64*            batchMin = (u64*)           (ws + 4153344);   // 64 B
    float*          ssf      = (float*)         (ws + 4153408);   // 320*1280*4 = 1,638,400 B
    float*          Sf       = (float*)         (ws + 5791808);   // 1,638,400 B
    unsigned short* dBf      = (unsigned short*)(ws + 7430208);   // 320*20*1280*2 = 16,384,000 B
    float*          bgf      = (float*)         (ws + 7430208);   // overlays dBf (dBf dead by then); 3,276,800 B

    k_protos    <<<dim3(VV),        dim3(512), 0, stream>>>(refc, coord, cls, protosT, batchMin);
    k_probC_part<<<dim3(BB*NTT*NG), dim3(THR), 0, stream>>>(codeC, protosT, dBf, ssf, Sf);
    k_finishC   <<<dim3(BB*25),     dim3(256), 0, stream>>>(dBf, ssf, Sf, probC, batchMin);
    k_minvec    <<<dim3(BB),        dim3(512), 0, stream>>>(batchMin, codeBG, minvecN);
    k_bg_part   <<<dim3(BB*NTT*NG), dim3(THR), 0, stream>>>(codeBG, minvecN, bgf);
    k_finishBG  <<<dim3(BB*25),     dim3(256), 0, stream>>>(bgf, probC, out);
}

// Round 11
// 66.889 us; speedup vs baseline: 1.5121x; 1.5121x over previous
//
#include <hip/hip_runtime.h>
#include <math.h>

#define BB 8
#define CC 512
#define HWSZ 6400
#define NN 100
#define HR 40
#define WR 40
#define VV 20        // N_CLASSES_FG
#define VO 21        // BG + FG
#define TPX 256      // pixels per tile
#define NT (HWSZ / TPX)      // 25 tiles

typedef unsigned long long u64;
typedef unsigned short u16;

// order-preserving float -> uint32 map (min float == min uint)
__device__ __forceinline__ unsigned mapf(float f) {
    unsigned b = __float_as_uint(f);
    return (b & 0x80000000u) ? ~b : (b | 0x80000000u);
}
// f32 -> bf16 round-nearest-even (validated r10)
__device__ __forceinline__ u16 f2bf(float f) {
    unsigned u = __float_as_uint(f);
    return (u16)((u + 0x7fffu + ((u >> 16) & 1u)) >> 16);
}
__device__ __forceinline__ float bf2f(u16 h) {
    return __uint_as_float(((unsigned)h) << 16);
}

// ---------------- K1: normalized prototypes, transposed [c][v] (r5 body) ----
__global__ __launch_bounds__(512) void k_protos(const float* __restrict__ refc,
                                                const int* __restrict__ coord,
                                                const int* __restrict__ cls,
                                                float* __restrict__ protosT,
                                                u64* __restrict__ batchMin,
                                                unsigned* __restrict__ batchCnt) {
    const int v = blockIdx.x;        // class
    const int c = threadIdx.x;       // channel
    if (v == 0 && c < BB) { batchMin[c] = ~0ull; batchCnt[c] = 0u; }

    float acc = 0.f;
    int cnt = 0;
    for (int n = 0; n < NN; ++n) {
        if (cls[n] == v) {           // uniform across block
            int y = coord[2 * n + 1];
            int x = coord[2 * n + 0];
            acc += refc[((size_t)(n * CC + c) * HR + y) * WR + x];
            ++cnt;
        }
    }
    acc /= fmaxf((float)cnt, 1.0f);

    float ss = acc * acc;
    #pragma unroll
    for (int off = 32; off; off >>= 1) ss += __shfl_xor(ss, off);
    __shared__ float sW[8];
    const int wave = c >> 6, lane = c & 63;
    if (lane == 0) sW[wave] = ss;
    __syncthreads();
    float tot = 0.f;
    #pragma unroll
    for (int w = 0; w < 8; ++w) tot += sW[w];
    float scale = 1.0f / fmaxf(sqrtf(tot), 1e-10f);

    protosT[c * VV + v] = acc * scale;
}

// ---------------- K2: partial prob_C sums, float4 streaming (r5 hot loop) ---
// grid = 8b x 25tiles x 2 channel-halves = 400; block = 256 = 4 waves.
// wave w owns channels [cg*256 + w*64, +64); lane owns float4 @ px 4*lane.
// Partials: ssS[blk][2][256] f32 (ss row, S=sum_v d row), dB[blk][20][256] bf16.
__global__ __launch_bounds__(256) void k_probC_part(const float* __restrict__ codeC,
                                                    const float* __restrict__ protosT,
                                                    float* __restrict__ ssSf,
                                                    u16* __restrict__ dBf) {
    __shared__ float red[4 * 11 * TPX];   // 45 KB

    const int tid  = threadIdx.x;
    const int w    = tid >> 6, lane = tid & 63;
    const int blk  = blockIdx.x;          // b*50 + tile*2 + cg
    const int cg   = blk & 1;
    const int tile = (blk >> 1) % NT;
    const int b    = blk / (2 * NT);
    const int c0   = __builtin_amdgcn_readfirstlane(cg * 256 + w * 64);

    const float* src = codeC + ((size_t)(b * CC + c0)) * HWSZ + tile * TPX + 4 * lane;
    const float* pt  = protosT + (size_t)c0 * VV;   // wave-uniform -> s_load

    float4 d[VV];
    #pragma unroll
    for (int v = 0; v < VV; ++v) d[v] = make_float4(0.f, 0.f, 0.f, 0.f);
    float4 ss = make_float4(0.f, 0.f, 0.f, 0.f);

    #pragma unroll 8
    for (int c = 0; c < 64; ++c) {
        float4 x = *(const float4*)(src + (size_t)c * HWSZ);
        ss.x = fmaf(x.x, x.x, ss.x);
        ss.y = fmaf(x.y, x.y, ss.y);
        ss.z = fmaf(x.z, x.z, ss.z);
        ss.w = fmaf(x.w, x.w, ss.w);
        const float* pr = pt + c * VV;
        #pragma unroll
        for (int v = 0; v < VV; ++v) {
            float p = pr[v];
            d[v].x = fmaf(x.x, p, d[v].x);
            d[v].y = fmaf(x.y, p, d[v].y);
            d[v].z = fmaf(x.z, p, d[v].z);
            d[v].w = fmaf(x.w, p, d[v].w);
        }
    }

    float* ssS = ssSf + (size_t)blk * (2 * TPX);
    u16*   dB  = dBf  + (size_t)blk * (VV * TPX);
    float S = 0.f;

    // round A: ss + d0..d9
    *(float4*)&red[(w * 11 + 0) * TPX + 4 * lane] = ss;
    #pragma unroll
    for (int r = 0; r < 10; ++r)
        *(float4*)&red[(w * 11 + 1 + r) * TPX + 4 * lane] = d[r];
    __syncthreads();
    {
        float t = red[tid] + red[11 * TPX + tid] + red[22 * TPX + tid] + red[33 * TPX + tid];
        ssS[tid] = t;   // ss row (f32)
    }
    #pragma unroll
    for (int r = 1; r <= 10; ++r) {
        int q = r * TPX + tid;
        float t = red[q] + red[11 * TPX + q] + red[22 * TPX + q] + red[33 * TPX + q];
        dB[(r - 1) * TPX + tid] = f2bf(t);
        S += t;
    }
    __syncthreads();

    // round B: d10..d19
    #pragma unroll
    for (int r = 0; r < 10; ++r)
        *(float4*)&red[(w * 11 + r) * TPX + 4 * lane] = d[10 + r];
    __syncthreads();
    #pragma unroll
    for (int r = 0; r < 10; ++r) {
        int q = r * TPX + tid;
        float t = red[q] + red[11 * TPX + q] + red[22 * TPX + q] + red[33 * TPX + q];
        dB[(10 + r) * TPX + tid] = f2bf(t);
        S += t;
    }
    ssS[TPX + tid] = S;   // S row (f32, argmin-accurate)
}

// ---------------- K2b: combine halves -> probC + psum + argmin + minvec -----
// grid = 8b x 25tiles = 200; block = 256 (thread = pixel).
// Last finisher per batch computes the normalized min_vec (done-counter, r7/r8).
__global__ __launch_bounds__(256) void k_finishC(const float* __restrict__ ssSf,
                                                 const u16* __restrict__ dBf,
                                                 const float* __restrict__ codeBG,
                                                 float* __restrict__ probC,
                                                 u64* __restrict__ batchMin,
                                                 unsigned* __restrict__ batchCnt,
                                                 float* __restrict__ minvecN) {
    __shared__ u64 sKey[4];
    __shared__ int sBLast;
    __shared__ unsigned sPix;
    __shared__ float sR[4];

    const int tid  = threadIdx.x;               // px
    const int lane = tid & 63, w = tid >> 6;
    const int tile = blockIdx.x % NT;
    const int b    = blockIdx.x / NT;

    const float* s0 = ssSf + (size_t)(b * 2 * NT + tile * 2) * (2 * TPX);
    const float* s1 = s0 + 2 * TPX;
    const u16*   d0 = dBf + (size_t)(b * 2 * NT + tile * 2) * (VV * TPX);
    const u16*   d1 = d0 + VV * TPX;

    float ssT = s0[tid] + s1[tid];
    float ST  = s0[TPX + tid] + s1[TPX + tid];
    float scale = 1.0f / fmaxf(sqrtf(ssT), 1e-10f);

    float* dst = probC + (size_t)b * VV * HWSZ + tile * TPX;
    #pragma unroll
    for (int v = 0; v < VV; ++v) {
        float dv = bf2f(d0[v * TPX + tid]) + bf2f(d1[v * TPX + tid]);
        dst[(size_t)v * HWSZ + tid] = dv * scale;
    }

    float psum = ST * scale;   // f32-accurate argmin key
    u64 key = ((u64)mapf(psum) << 32) | (unsigned)(tile * TPX + tid);
    #pragma unroll
    for (int off = 32; off; off >>= 1) {
        u64 o = __shfl_xor(key, off);
        if (o < key) key = o;
    }
    if (lane == 0) sKey[w] = key;
    __syncthreads();
    if (tid == 0) {
        u64 kk = sKey[0];
        kk = sKey[1] < kk ? sKey[1] : kk;
        kk = sKey[2] < kk ? sKey[2] : kk;
        kk = sKey[3] < kk ? sKey[3] : kk;
        atomicMin(&batchMin[b], kk);
        __threadfence();
        unsigned old = atomicAdd(&batchCnt[b], 1u);
        sBLast = (old == NT - 1) ? 1 : 0;
    }
    __syncthreads();

    // last finisher of this batch: normalized min_vec
    if (!sBLast) return;
    if (tid == 0) {
        __threadfence();
        u64 kk = atomicMin(&batchMin[b], ~0ull);   // identity RMW = coherent read
        sPix = (unsigned)(kk & 0xFFFFFFFFull);
    }
    __syncthreads();
    const int pix = (int)sPix;
    float x0 = codeBG[((size_t)(b * CC + tid)) * HWSZ + pix];
    float x1 = codeBG[((size_t)(b * CC + 256 + tid)) * HWSZ + pix];
    float s2 = fmaf(x0, x0, x1 * x1);
    #pragma unroll
    for (int off = 32; off; off >>= 1) s2 += __shfl_xor(s2, off);
    if (lane == 0) sR[w] = s2;
    __syncthreads();
    float totq = sR[0] + sR[1] + sR[2] + sR[3];
    float sc = 1.0f / fmaxf(sqrtf(totq), 1e-10f);
    minvecN[b * CC + tid] = x0 * sc;
    minvecN[b * CC + 256 + tid] = x1 * sc;
}

// ---------------- K4: partial prob_BG sums, float4 streaming (r5 body) ------
// Writes partBG[blk][2][256]  (ss row, dg row).
__global__ __launch_bounds__(256) void k_bg_part(const float* __restrict__ codeBG,
                                                 const float* __restrict__ minvecN,
                                                 float* __restrict__ partBG) {
    __shared__ float red[4 * 2 * TPX];   // 8 KB

    const int tid  = threadIdx.x;
    const int w    = tid >> 6, lane = tid & 63;
    const int blk  = blockIdx.x;
    const int cg   = blk & 1;
    const int tile = (blk >> 1) % NT;
    const int b    = blk / (2 * NT);
    const int c0   = __builtin_amdgcn_readfirstlane(cg * 256 + w * 64);

    const float* src = codeBG + ((size_t)(b * CC + c0)) * HWSZ + tile * TPX + 4 * lane;
    const float* mv  = minvecN + b * CC + c0;   // wave-uniform -> s_load

    float4 ss = make_float4(0.f, 0.f, 0.f, 0.f);
    float4 dg = make_float4(0.f, 0.f, 0.f, 0.f);

    #pragma unroll 8
    for (int c = 0; c < 64; ++c) {
        float4 x = *(const float4*)(src + (size_t)c * HWSZ);
        float m = mv[c];
        ss.x = fmaf(x.x, x.x, ss.x);
        ss.y = fmaf(x.y, x.y, ss.y);
        ss.z = fmaf(x.z, x.z, ss.z);
        ss.w = fmaf(x.w, x.w, ss.w);
        dg.x = fmaf(x.x, m, dg.x);
        dg.y = fmaf(x.y, m, dg.y);
        dg.z = fmaf(x.z, m, dg.z);
        dg.w = fmaf(x.w, m, dg.w);
    }

    *(float4*)&red[(w * 2 + 0) * TPX + 4 * lane] = ss;
    *(float4*)&red[(w * 2 + 1) * TPX + 4 * lane] = dg;
    __syncthreads();

    float* dstp = partBG + (size_t)blk * (2 * TPX);
    for (int q = tid; q < 2 * TPX; q += 256) {
        float t = red[q] + red[2 * TPX + q] + red[4 * TPX + q] + red[6 * TPX + q];
        dstp[q] = t;
    }
}

// ---------------- K4b: combine halves -> prob_BG + softmax + out (r5 body) --
__global__ __launch_bounds__(256) void k_finishBG(const float* __restrict__ partBG,
                                                  const float* __restrict__ probC,
                                                  float* __restrict__ out) {
    const int tid  = threadIdx.x;               // px
    const int tile = blockIdx.x % NT;
    const int b    = blockIdx.x / NT;

    const float* q0 = partBG + ((size_t)(b * 2 * NT + tile * 2)) * (2 * TPX);
    const float* q1 = q0 + 2 * TPX;

    float ssT = q0[tid] + q1[tid];
    float dgT = q0[TPX + tid] + q1[TPX + tid];
    float pbg = dgT * (1.0f / fmaxf(sqrtf(ssT), 1e-10f));

    float pv[VO];
    pv[0] = pbg;
    const float* pc = probC + (size_t)b * VV * HWSZ + tile * TPX + tid;
    #pragma unroll
    for (int v = 0; v < VV; ++v) pv[v + 1] = pc[(size_t)v * HWSZ];

    float m = pv[0];
    #pragma unroll
    for (int i = 1; i < VO; ++i) m = fmaxf(m, pv[i]);
    float se = 0.f;
    #pragma unroll
    for (int i = 0; i < VO; ++i) { pv[i] = __expf(pv[i] - m); se += pv[i]; }
    float inv = 1.0f / se;

    float* dstp = out + (size_t)b * VO * HWSZ + tile * TPX + tid;
    #pragma unroll
    for (int i = 0; i < VO; ++i) dstp[(size_t)i * HWSZ] = pv[i] * inv;
}

extern "C" void kernel_launch(void* const* d_in, const int* in_sizes, int n_in,
                              void* d_out, int out_size, void* d_ws, size_t ws_size,
                              hipStream_t stream) {
    const float* codeC  = (const float*)d_in[0];
    const float* codeBG = (const float*)d_in[1];
    const float* refc   = (const float*)d_in[2];
    // d_in[3] (ref_code_bg) unused by the reference
    const int* coord = (const int*)d_in[4];
    const int* cls   = (const int*)d_in[5];
    float* out = (float*)d_out;

    char* ws = (char*)d_ws;
    float*    protosT  = (float*)   (ws);              // 40,960 B  [c][v]
    float*    probC    = (float*)   (ws + 40960);      // 4,096,000 B
    float*    minvecN  = (float*)   (ws + 4136960);    // 16,384 B
    u64*      batchMin = (u64*)     (ws + 4153344);    // 64 B
    unsigned* batchCnt = (unsigned*)(ws + 4153408);    // 32 B (pad to 64)
    float*    ssSf     = (float*)   (ws + 4153472);    // 400*2*256*4 = 819,200 B
    u16*      dBf      = (u16*)     (ws + 4972672);    // 400*20*256*2 = 4,096,000 B
    float*    partBG   = (float*)   (ws + 9068672);    // 400*2*256*4 = 819,200 B

    k_protos    <<<dim3(VV),          dim3(512), 0, stream>>>(refc, coord, cls, protosT,
                                                              batchMin, batchCnt);
    k_probC_part<<<dim3(BB * NT * 2), dim3(256), 0, stream>>>(codeC, protosT, ssSf, dBf);
    k_finishC   <<<dim3(BB * NT),     dim3(256), 0, stream>>>(ssSf, dBf, codeBG, probC,
                                                              batchMin, batchCnt, minvecN);
    k_bg_part   <<<dim3(BB * NT * 2), dim3(256), 0, stream>>>(codeBG, minvecN, partBG);
    k_finishBG  <<<dim3(BB * NT),     dim3(256), 0, stream>>>(partBG, probC, out);
}